// Round 1
// baseline (410.914 us; speedup 1.0000x reference)
//
#include <hip/hip_runtime.h>
#include <math.h>

// Problem constants (fixed by reference setup_inputs)
#define HH 512
#define WW 512
#define ITERS 10
#define TW 128
#define TH 32
#define NBX (WW / TW)     // 4
#define NBY (HH / TH)     // 16
#define IMG_W (TW + 4)    // 132
#define IMG_H (TH + 4)    // 36
#define E_W (TW + 2)      // 130
#define E_H (TH + 2)      // 34

__device__ __forceinline__ float sigmoidf_(float x) {
    return 1.0f / (1.0f + __expf(-x));
}

// One soft_skel iteration for one chain:
//   E = soft_erode(img)  (written to dst -> next img)
//   D = soft_dilate(E)   (= "opened")
//   r = relu(img - D); accumulate wsum += w*r, rsum += r per block.
// Erode pads with +inf (min ignores OOB); dilate pads with -inf, which we
// realize by forcing E = -inf at out-of-image positions in the halo tile.
__global__ __launch_bounds__(256, 4)
void clDice_iter_kernel(const float* __restrict__ src, float* __restrict__ dst,
                        const float* __restrict__ wsrc,
                        float* __restrict__ partials,
                        int apply_sig_src, int apply_sig_w, int slot_base)
{
    __shared__ float simg[IMG_H][IMG_W];
    __shared__ float sE[E_H][E_W];

    const int tid = threadIdx.x;
    const int bx = blockIdx.x;            // 0..NBX-1
    const int by = blockIdx.y % NBY;      // 0..NBY-1
    const int b  = blockIdx.y / NBY;      // batch
    const int r0 = by * TH;
    const int c0 = bx * TW;
    const size_t base = (size_t)b * (HH * WW);

    // ---- stage 1: load img tile with halo 2 (OOB = +inf) ----
    for (int i = tid; i < IMG_H * IMG_W; i += 256) {
        int lr = i / IMG_W, lc = i % IMG_W;
        int gr = r0 - 2 + lr, gc = c0 - 2 + lc;
        float v = INFINITY;
        if (gr >= 0 && gr < HH && gc >= 0 && gc < WW) {
            v = src[base + (size_t)gr * WW + gc];
            if (apply_sig_src) v = sigmoidf_(v);
        }
        simg[lr][lc] = v;
    }
    __syncthreads();

    // ---- stage 2: erode into sE with halo 1 (OOB positions = -inf) ----
    for (int i = tid; i < E_H * E_W; i += 256) {
        int er = i / E_W, ec = i % E_W;
        int gr = r0 - 1 + er, gc = c0 - 1 + ec;
        float e = -INFINITY;
        if (gr >= 0 && gr < HH && gc >= 0 && gc < WW) {
            float c  = simg[er + 1][ec + 1];
            float vv = fminf(fminf(simg[er][ec + 1], c), simg[er + 2][ec + 1]);
            float hh = fminf(fminf(simg[er + 1][ec], c), simg[er + 1][ec + 2]);
            e = fminf(vv, hh);
        }
        sE[er][ec] = e;
    }
    __syncthreads();

    // ---- stage 3: dilate, accumulate, write E out ----
    float wsum = 0.f, rsum = 0.f;
    for (int i = tid; i < TH * TW; i += 256) {
        int ir = i / TW, ic = i % TW;
        size_t g = base + (size_t)(r0 + ir) * WW + (c0 + ic);
        float d = sE[ir][ic];
        d = fmaxf(d, sE[ir][ic + 1]);
        d = fmaxf(d, sE[ir][ic + 2]);
        d = fmaxf(d, sE[ir + 1][ic]);
        d = fmaxf(d, sE[ir + 1][ic + 1]);
        d = fmaxf(d, sE[ir + 1][ic + 2]);
        d = fmaxf(d, sE[ir + 2][ic]);
        d = fmaxf(d, sE[ir + 2][ic + 1]);
        d = fmaxf(d, sE[ir + 2][ic + 2]);
        float v = simg[ir + 2][ic + 2];
        float r = fmaxf(v - d, 0.f);
        float w = wsrc[g];
        if (apply_sig_w) w = sigmoidf_(w);
        wsum += w * r;
        rsum += r;
        dst[g] = sE[ir + 1][ic + 1];
    }

    // ---- block reduction (deterministic): wave shfl + LDS combine ----
    for (int off = 32; off > 0; off >>= 1) {
        wsum += __shfl_down(wsum, off, 64);
        rsum += __shfl_down(rsum, off, 64);
    }
    __shared__ float swred[4][2];
    int wave = tid >> 6, lane = tid & 63;
    if (lane == 0) { swred[wave][0] = wsum; swred[wave][1] = rsum; }
    __syncthreads();
    if (tid == 0) {
        float Wt = 0.f, Rt = 0.f;
        for (int w = 0; w < 4; ++w) { Wt += swred[w][0]; Rt += swred[w][1]; }
        int blk = blockIdx.y * gridDim.x + blockIdx.x;
        int slot = slot_base + blk;
        partials[2 * slot]     = Wt;
        partials[2 * slot + 1] = Rt;
    }
}

// Deterministic final reduction of all per-block partials + loss formula.
__global__ void clDice_finalize_kernel(const float* __restrict__ partials,
                                       float* __restrict__ out, int nblk)
{
    const int tid = threadIdx.x;
    const int npairs = ITERS * nblk;  // per chain
    double a0 = 0, a1 = 0, a2 = 0, a3 = 0; // chain0: w,r ; chain1: w,r
    for (int i = tid; i < npairs; i += 256) {
        int t = i / nblk, blk = i % nblk;
        int s0 = (t * 2 + 0) * nblk + blk;
        int s1 = (t * 2 + 1) * nblk + blk;
        a0 += (double)partials[2 * s0];
        a1 += (double)partials[2 * s0 + 1];
        a2 += (double)partials[2 * s1];
        a3 += (double)partials[2 * s1 + 1];
    }
    __shared__ double red[256][4];
    red[tid][0] = a0; red[tid][1] = a1; red[tid][2] = a2; red[tid][3] = a3;
    __syncthreads();
    for (int s = 128; s > 0; s >>= 1) {
        if (tid < s)
            for (int q = 0; q < 4; ++q) red[tid][q] += red[tid + s][q];
        __syncthreads();
    }
    if (tid == 0) {
        double t_skelpred = red[0][0];  // sum(target * skel_pred)  (chain 0)
        double skelpred   = red[0][1];  // sum(skel_pred)
        double p_skelgt   = red[0][2];  // sum(p * skel_gt)         (chain 1)
        double skelgt     = red[0][3];  // sum(skel_gt)
        double tprec = p_skelgt / (skelgt + 1e-6);
        double tsens = t_skelpred / (skelpred + 1e-6);
        double cl = 2.0 * tprec * tsens / (tprec + tsens + 1e-6);
        out[0] = (float)(1.0 - cl);
    }
}

extern "C" void kernel_launch(void* const* d_in, const int* in_sizes, int n_in,
                              void* d_out, int out_size, void* d_ws, size_t ws_size,
                              hipStream_t stream) {
    const float* pred   = (const float*)d_in[0];
    const float* target = (const float*)d_in[1];
    float* out = (float*)d_out;

    const int B = in_sizes[0] / (HH * WW);     // 16
    const size_t N = (size_t)B * HH * WW;
    const int nblk = NBX * NBY * B;            // blocks per dispatch

    float* buf0 = (float*)d_ws;
    float* buf1 = buf0 + N;
    float* partials = buf1 + N;                // ITERS*2*nblk*2 floats

    dim3 grid(NBX, NBY * B);
    dim3 blk(256);

    // chain 0: img = sigmoid(pred), weight = target
    // chain 1: img = target,        weight = sigmoid(pred)
    for (int chain = 0; chain < 2; ++chain) {
        const float* wsrc = (chain == 0) ? target : pred;
        const int sigw = (chain == 1);
        for (int t = 0; t < ITERS; ++t) {
            const float* src;
            float* dst = (t & 1) ? buf1 : buf0;
            if (t == 0) src = (chain == 0) ? pred : target;
            else        src = (t & 1) ? buf0 : buf1;
            const int sigs = (t == 0 && chain == 0);
            const int slot_base = (t * 2 + chain) * nblk;
            hipLaunchKernelGGL(clDice_iter_kernel, grid, blk, 0, stream,
                               src, dst, wsrc, partials, sigs, sigw, slot_base);
        }
    }
    hipLaunchKernelGGL(clDice_finalize_kernel, dim3(1), dim3(256), 0, stream,
                       partials, out, nblk);
}

// Round 2
// 119.389 us; speedup vs baseline: 3.4418x; 3.4418x over previous
//
#include <hip/hip_runtime.h>
#include <math.h>

// Problem constants (fixed by reference setup_inputs)
#define HH 512
#define WW 512
#define NBATCH 16
#define RV 32                     // output rows per vertical strip
#define SV (HH/RV)                // 16
#define SH 5                      // horizontal strips (stride 102 cols)
#define NTASK (2*NBATCH*SH*SV)    // 2560 wave tasks
#define NSTEP (RV + 23)           // 55 pipeline steps per strip
#define FINF  (__builtin_huge_valf())

__device__ __forceinline__ float sigf(float x) { return 1.0f / (1.0f + __expf(-x)); }
__device__ __forceinline__ float bperm(int addr, float v) {
    return __int_as_float(__builtin_amdgcn_ds_bpermute(addr, __float_as_int(v)));
}

// Wave-autonomous fused soft_skel strip:
//  - 11 erosion levels, 3-row register windows each (W[t] = img_t rows, newest = f-t
//    after Phase A of step f; img_{t+1} == E_t so windows chain).
//  - Phase B (before shifting) computes opened_t at row q=f-t-3 from last step's
//    windows: dilate = maxH3(maxV3(E_t)), skel contribution accumulated into a
//    10-row rolling register ring sk[] (sk[0] = row f-12, finalized each step).
//  - Phase A shifts windows, pushes img_0 row f, erodes level-by-level.
//  - Horizontal exchange: ds_bpermute lane+-1 (wave64). Column pads via static
//    per-lane masks: erode-store forces +inf at image-OOB cols (max(e,-mD)),
//    dilate input forces -inf (min(cm,mD)). Row pads via uniform selects (GUARD).
template<bool GUARD>
__device__ __forceinline__ void do_strip(
    const float* __restrict__ ip, const float* __restrict__ wp,
    bool sigI, bool sigW, int r0,
    bool ok0, bool ok1, bool useX, bool useY,
    float mDx, float mDy, int aL, int aR,
    float* __restrict__ partials, int wid, int lane)
{
    float2 W[11][3], sk[10];
#pragma unroll
    for (int t = 0; t < 11; ++t)
#pragma unroll
        for (int j = 0; j < 3; ++j) W[t][j] = make_float2(FINF, FINF);
#pragma unroll
    for (int j = 0; j < 10; ++j) sk[j] = make_float2(0.f, 0.f);
    float2 wsum = make_float2(0.f, 0.f), rsum = make_float2(0.f, 0.f);

    for (int s = 0; s < NSTEP; ++s) {
        const int f = r0 - 11 + s;

        // ---- load img_0 row f (issued early; rows OOB -> +inf) ----
        float2 nv;
        if (!GUARD || (f >= 0 && f < HH)) {
            float2 t0 = *(const float2*)(ip);
            float x = sigI ? sigf(t0.x) : t0.x;
            float y = sigI ? sigf(t0.y) : t0.y;
            nv.x = ok0 ? x : FINF;
            nv.y = ok1 ? y : FINF;
        } else { nv.x = FINF; nv.y = FINF; }
        ip += WW;

        // ---- shift skel ring: sk[j] now holds row f-12+j ----
#pragma unroll
        for (int j = 0; j < 9; ++j) sk[j] = sk[j + 1];

        // ---- Phase B: dilate + accumulate, level t at row q = f-t-3 ----
        // Uses PRE-shift windows (all inputs from last step -> bperms independent).
#pragma unroll
        for (int t = 0; t < 10; ++t) {
            float2 b0 = W[t + 1][0], b1 = W[t + 1][1], b2 = W[t + 1][2]; // E_t rows q-1..q+1
            if (GUARD) {
                if (f - t - 4 < 0 || f - t - 4 >= HH) { b0.x = -FINF; b0.y = -FINF; }
                if (f - t - 3 < 0 || f - t - 3 >= HH) { b1.x = -FINF; b1.y = -FINF; }
                if (f - t - 2 < 0 || f - t - 2 >= HH) { b2.x = -FINF; b2.y = -FINF; }
            }
            float cmx = fmaxf(fmaxf(b0.x, b1.x), b2.x);
            float cmy = fmaxf(fmaxf(b0.y, b1.y), b2.y);
            cmx = fminf(cmx, mDx);           // image-OOB cols act as -inf for dilate
            cmy = fminf(cmy, mDy);
            float Lc = bperm(aL, cmy);       // col c0-1 (lane-1 .y)
            float Rc = bperm(aR, cmx);       // col c1+1 (lane+1 .x)
            float dx = fmaxf(fmaxf(cmx, Lc), cmy);
            float dy = fmaxf(fmaxf(cmy, cmx), Rc);
            float2 iq = W[t][0];             // img_t row q
            float rx = fmaxf(iq.x - dx, 0.f);
            float ry = fmaxf(iq.y - dy, 0.f);
            rx = useX ? rx : 0.f;            // static col ownership mask (kills junk/NaN)
            ry = useY ? ry : 0.f;
            if (t == 0) { sk[9].x = rx;       sk[9].y = ry; }
            else        { sk[9 - t].x += rx;  sk[9 - t].y += ry; }
        }

        // ---- finalize skel row fr = f-12 (all 10 levels contributed) ----
        const int fr = f - 12;
        if (fr >= r0 && fr < r0 + RV) {
            float2 wv = *(const float2*)(wp);
            float wx = sigW ? sigf(wv.x) : wv.x;
            float wy = sigW ? sigf(wv.y) : wv.y;
            wx = ok0 ? wx : 0.f;
            wy = ok1 ? wy : 0.f;
            wsum.x += wx * sk[0].x; wsum.y += wy * sk[0].y;
            rsum.x += sk[0].x;      rsum.y += sk[0].y;
            wp += WW;
        }

        // ---- Phase A: shift windows + erode chain (push img_0 row f) ----
        float2 nr = nv;
#pragma unroll
        for (int t = 0; t < 10; ++t) {
            W[t][0] = W[t][1]; W[t][1] = W[t][2]; W[t][2] = nr;
            float2 a0 = W[t][0], a1 = W[t][1], a2 = W[t][2];   // rows f-t-2..f-t
            if (GUARD) {
                if (f - t - 2 < 0 || f - t - 2 >= HH) { a0.x = FINF; a0.y = FINF; }
                if (f - t - 1 < 0 || f - t - 1 >= HH) { a1.x = FINF; a1.y = FINF; }
                if (f - t     < 0 || f - t     >= HH) { a2.x = FINF; a2.y = FINF; }
            }
            float mvx = fminf(fminf(a0.x, a1.x), a2.x);
            float mvy = fminf(fminf(a0.y, a1.y), a2.y);
            float Le = bperm(aL, a1.y);
            float Re = bperm(aR, a1.x);
            float ex = fminf(fminf(mvx, Le), a1.y);
            float ey = fminf(fminf(mvy, a1.x), Re);
            ex = fmaxf(ex, -mDx);            // image-OOB cols stay +inf for erode
            ey = fmaxf(ey, -mDy);
            nr.x = ex; nr.y = ey;            // = img_{t+1} row f-t-1
        }
        W[10][0] = W[10][1]; W[10][1] = W[10][2]; W[10][2] = nr;
    }

    // ---- wave reduction (deterministic) ----
    float pw = wsum.x + wsum.y;
    float pr = rsum.x + rsum.y;
#pragma unroll
    for (int off = 32; off; off >>= 1) {
        pw += __shfl_down(pw, off, 64);
        pr += __shfl_down(pr, off, 64);
    }
    if (lane == 0) { partials[2 * wid] = pw; partials[2 * wid + 1] = pr; }
}

__global__ __launch_bounds__(256)
void cld_main(const float* __restrict__ pred, const float* __restrict__ target,
              float* __restrict__ partials)
{
    const int wid  = blockIdx.x * 4 + (threadIdx.x >> 6);
    const int lane = threadIdx.x & 63;

    int t_ = wid;
    const int chain = t_ / (NBATCH * SH * SV);  t_ -= chain * (NBATCH * SH * SV);
    const int b     = t_ / (SH * SV);           t_ -= b * (SH * SV);
    const int u     = t_ / SV;
    const int v     = t_ - u * SV;
    const int r0    = v * RV;
    const int cbase = u * 102 - 12;             // even -> 8B-aligned float2 loads
    const int UW    = (u == 4) ? 104 : 102;

    const int c0 = cbase + 2 * lane;
    const int c1 = c0 + 1;
    const bool ok0 = (c0 >= 0) && (c0 < WW);
    const bool ok1 = (c1 >= 0) && (c1 < WW);
    const int wc0 = 2 * lane;
    const bool useX = (wc0     >= 12) && (wc0     < 12 + UW);
    const bool useY = (wc0 + 1 >= 12) && (wc0 + 1 < 12 + UW);
    const float mDx = ok0 ? FINF : -FINF;
    const float mDy = ok1 ? FINF : -FINF;
    const int cc = min(max(c0, 0), WW - 2);
    const int aL = ((lane + 63) & 63) << 2;
    const int aR = ((lane + 1) & 63) << 2;

    const float* ibase = (chain == 0) ? pred : target;
    const float* wbase = (chain == 0) ? target : pred;
    const bool sigI = (chain == 0);
    const bool sigW = (chain == 1);
    const float* ip = ibase + (size_t)b * HH * WW + (ptrdiff_t)(r0 - 11) * WW + cc;
    const float* wp = wbase + (size_t)b * HH * WW + (size_t)r0 * WW + cc;

    if (v == 0 || v == SV - 1)
        do_strip<true >(ip, wp, sigI, sigW, r0, ok0, ok1, useX, useY, mDx, mDy, aL, aR, partials, wid, lane);
    else
        do_strip<false>(ip, wp, sigI, sigW, r0, ok0, ok1, useX, useY, mDx, mDy, aL, aR, partials, wid, lane);
}

// Deterministic final reduction + loss formula.
__global__ void cld_final(const float* __restrict__ partials, float* __restrict__ out)
{
    const int tid = threadIdx.x;
    const int PC = NTASK / 2;   // tasks per chain
    double a0 = 0, a1 = 0, a2 = 0, a3 = 0;
    for (int i = tid; i < PC; i += 256) {
        a0 += (double)partials[2 * i];                 // chain0: sum(target*skel_pred)
        a1 += (double)partials[2 * i + 1];             // chain0: sum(skel_pred)
        a2 += (double)partials[2 * (PC + i)];          // chain1: sum(p*skel_gt)
        a3 += (double)partials[2 * (PC + i) + 1];      // chain1: sum(skel_gt)
    }
    __shared__ double red[256][4];
    red[tid][0] = a0; red[tid][1] = a1; red[tid][2] = a2; red[tid][3] = a3;
    __syncthreads();
    for (int s2 = 128; s2 > 0; s2 >>= 1) {
        if (tid < s2) {
            red[tid][0] += red[tid + s2][0]; red[tid][1] += red[tid + s2][1];
            red[tid][2] += red[tid + s2][2]; red[tid][3] += red[tid + s2][3];
        }
        __syncthreads();
    }
    if (tid == 0) {
        double tsens = red[0][0] / (red[0][1] + 1e-6);
        double tprec = red[0][2] / (red[0][3] + 1e-6);
        double cl = 2.0 * tprec * tsens / (tprec + tsens + 1e-6);
        out[0] = (float)(1.0 - cl);
    }
}

extern "C" void kernel_launch(void* const* d_in, const int* in_sizes, int n_in,
                              void* d_out, int out_size, void* d_ws, size_t ws_size,
                              hipStream_t stream) {
    const float* pred   = (const float*)d_in[0];
    const float* target = (const float*)d_in[1];
    float* out = (float*)d_out;
    float* partials = (float*)d_ws;          // NTASK*2 floats = 20 KB

    hipLaunchKernelGGL(cld_main, dim3(NTASK / 4), dim3(256), 0, stream,
                       pred, target, partials);
    hipLaunchKernelGGL(cld_final, dim3(1), dim3(256), 0, stream, partials, out);
}